// Round 2
// baseline (2679.068 us; speedup 1.0000x reference)
//
#include <hip/hip_runtime.h>

// Problem constants
#define NROWS   16384      // 16*32*32 flattened (b,h,w) rows
#define KCODES  8192
#define CDIM    256
#define HWS     1024       // 32*32
#define BSTRIDE 262144     // 256*1024 floats per batch in z / out

// Workspace layout (float-unit offsets)
#define WS_AN   0                         // ||x||^2 per row       [16384]
#define WS_CE   16384                     // ||e||^2 per code      [8192]
#define WS_CD   24576                     // cand dist [n*4+slice] [65536]
#define WS_CI   90112                     // cand idx  (int)       [65536]
#define WS_IDX  155648                    // final idx (int)       [16384]
#define WS_LOSS 172032                    // loss accumulator      [1]

// -------- row norms, replicating numpy pairwise_sum order exactly --------
__global__ void rownorm_z_k(const float* __restrict__ z, float* __restrict__ An) {
#pragma clang fp contract(off)
  int n = blockIdx.x * 256 + threadIdx.x;                    // 16384 threads
  const float* base = z + ((size_t)(n >> 10)) * BSTRIDE + (n & 1023);
  float hs[2];
  for (int h = 0; h < 2; ++h) {
    float r[8];
#pragma unroll
    for (int j = 0; j < 8; ++j) { float v = base[(size_t)(h * 128 + j) * HWS]; r[j] = v * v; }
    for (int m = 1; m < 16; ++m) {
#pragma unroll
      for (int j = 0; j < 8; ++j) { float v = base[(size_t)(h * 128 + m * 8 + j) * HWS]; r[j] += v * v; }
    }
    hs[h] = ((r[0] + r[1]) + (r[2] + r[3])) + ((r[4] + r[5]) + (r[6] + r[7]));
  }
  An[n] = hs[0] + hs[1];
}

__global__ void rownorm_e_k(const float* __restrict__ emb, float* __restrict__ Ce) {
#pragma clang fp contract(off)
  int n = blockIdx.x * 256 + threadIdx.x;                    // 8192 threads
  const float* base = emb + (size_t)n * CDIM;
  float hs[2];
  for (int h = 0; h < 2; ++h) {
    float r[8];
#pragma unroll
    for (int j = 0; j < 8; ++j) { float v = base[h * 128 + j]; r[j] = v * v; }
    for (int m = 1; m < 16; ++m) {
#pragma unroll
      for (int j = 0; j < 8; ++j) { float v = base[h * 128 + m * 8 + j]; r[j] += v * v; }
    }
    hs[h] = ((r[0] + r[1]) + (r[2] + r[3])) + ((r[4] + r[5]) + (r[6] + r[7]));
  }
  Ce[n] = hs[0] + hs[1];
}

// -------- fused distance + argmin --------
// 1024 blocks = 256 row-tiles (64 rows) x 4 code-slices (2048 codes each).
// 256 threads = 32 tx (codes, 4 each) x 8 ty (rows, 8 each). Micro-tile 8x4.
// amdgpu_waves_per_eu(3,3): pin occupancy target. Round-1 showed
// __launch_bounds__(256,4) let LLVM chase 8 waves/EU -> 64 VGPRs + 4.4 GB of
// scratch spill traffic (WRITE_SIZE counter). Cap 512/3=170 regs, need ~130.
// As stride 21 (was 20): store bank pattern (20j+a_c)%32 covers all 32 banks
// 2-way (free, m136); stride 20 gave 8-way (8 banks only) -> 7.9e7 conflicts.
__global__ void __launch_bounds__(256)
__attribute__((amdgpu_waves_per_eu(3, 3)))
vq_argmin_k(const float* __restrict__ z, const float* __restrict__ emb,
            const float* __restrict__ An, const float* __restrict__ Ce,
            float* __restrict__ cand_d, int* __restrict__ cand_i) {
  __shared__ float As[64 * 21];    // [row][c_local], stride 21 breaks store conflicts
  __shared__ float Bs[16 * 132];   // [c_local][code], 2-way max on stores (free)
  __shared__ float redd[64 * 32];
  __shared__ int   redi[64 * 32];

  const int t  = threadIdx.x;
  const int tx = t & 31;
  const int ty = t >> 5;
  const int tile  = blockIdx.x >> 2;
  const int slice = blockIdx.x & 3;
  const int rbase = tile * 64;
  const int k0    = slice * 2048;

  const float* zb = z + ((size_t)(rbase >> 10)) * BSTRIDE + (rbase & 1023);

  float A_reg[8];
#pragma unroll
  for (int ri = 0; ri < 8; ++ri) A_reg[ri] = An[rbase + ty * 8 + ri];

  float best[8];
  int   bidx[8];
#pragma unroll
  for (int ri = 0; ri < 8; ++ri) { best[ri] = 3.4028235e38f; bidx[ri] = 0; }

  float acc[8][4];
#pragma unroll
  for (int ri = 0; ri < 8; ++ri)
#pragma unroll
    for (int ki = 0; ki < 4; ++ki) acc[ri][ki] = 0.f;

  // staging thread mappings
  const int a_c  = t >> 4;          // c_local 0..15
  const int a_hw = (t & 15) * 4;    // 4 consecutive hw (rows) via float4
  const int b_ks = t >> 2;          // code 0..63 (and +64)
  const int b_cp = (t & 3) * 4;     // c_local offset 0/4/8/12 (64B-contig rows)

  float4 pa, pb0, pb1;
  {
    pa = *(const float4*)(zb + (size_t)(a_c) * HWS + a_hw);
    pb0 = *(const float4*)(emb + (size_t)(k0 + b_ks) * CDIM + b_cp);
    pb1 = *(const float4*)(emb + (size_t)(k0 + b_ks + 64) * CDIM + b_cp);
  }

  const int iters = 16 * (2048 / 128);   // 16 c-chunks * 16 code-chunks = 256
  for (int it = 0; it < iters; ++it) {
    const int cc = it & 15;
    const int kb = k0 + (it >> 4) * 128;

    __syncthreads();                      // prior compute done with As/Bs
    As[(a_hw + 0) * 21 + a_c] = pa.x;     // transpose hw-major load -> [row][c]
    As[(a_hw + 1) * 21 + a_c] = pa.y;
    As[(a_hw + 2) * 21 + a_c] = pa.z;
    As[(a_hw + 3) * 21 + a_c] = pa.w;
    Bs[(b_cp + 0) * 132 + b_ks] = pb0.x;
    Bs[(b_cp + 1) * 132 + b_ks] = pb0.y;
    Bs[(b_cp + 2) * 132 + b_ks] = pb0.z;
    Bs[(b_cp + 3) * 132 + b_ks] = pb0.w;
    Bs[(b_cp + 0) * 132 + b_ks + 64] = pb1.x;
    Bs[(b_cp + 1) * 132 + b_ks + 64] = pb1.y;
    Bs[(b_cp + 2) * 132 + b_ks + 64] = pb1.z;
    Bs[(b_cp + 3) * 132 + b_ks + 64] = pb1.w;
    __syncthreads();                      // staged data visible

    // prefetch next chunk into registers BEFORE compute (latency hidden)
    if (it + 1 < iters) {
      const int ncc = (it + 1) & 15;
      const int nkb = k0 + ((it + 1) >> 4) * 128;
      pa = *(const float4*)(zb + (size_t)(ncc * 16 + a_c) * HWS + a_hw);
      pb0 = *(const float4*)(emb + (size_t)(nkb + b_ks) * CDIM + ncc * 16 + b_cp);
      pb1 = *(const float4*)(emb + (size_t)(nkb + b_ks + 64) * CDIM + ncc * 16 + b_cp);
    }

    // 8x4 micro-tile over 16 c: 512 fp32 FMAs / thread
#pragma unroll
    for (int g = 0; g < 4; ++g) {
      const float4 b0 = *(const float4*)&Bs[(g * 4 + 0) * 132 + tx * 4];
      const float4 b1 = *(const float4*)&Bs[(g * 4 + 1) * 132 + tx * 4];
      const float4 b2 = *(const float4*)&Bs[(g * 4 + 2) * 132 + tx * 4];
      const float4 b3 = *(const float4*)&Bs[(g * 4 + 3) * 132 + tx * 4];
#pragma unroll
      for (int ri = 0; ri < 8; ++ri) {
        const float4 a = *(const float4*)&As[(ty * 8 + ri) * 21 + g * 4];
        acc[ri][0] = fmaf(a.x, b0.x, fmaf(a.y, b1.x, fmaf(a.z, b2.x, fmaf(a.w, b3.x, acc[ri][0]))));
        acc[ri][1] = fmaf(a.x, b0.y, fmaf(a.y, b1.y, fmaf(a.z, b2.y, fmaf(a.w, b3.y, acc[ri][1]))));
        acc[ri][2] = fmaf(a.x, b0.z, fmaf(a.y, b1.z, fmaf(a.z, b2.z, fmaf(a.w, b3.z, acc[ri][2]))));
        acc[ri][3] = fmaf(a.x, b0.w, fmaf(a.y, b1.w, fmaf(a.z, b2.w, fmaf(a.w, b3.w, acc[ri][3]))));
      }
    }

    if (cc == 15) {
      // fold: dist = (A - 2*dot) + C with np's elementwise fp32 rounding.
      // k ascending + strict < keeps lowest-index min, matching np.argmin ties.
      const int kk = kb + tx * 4;
      const float ce0 = Ce[kk + 0], ce1 = Ce[kk + 1], ce2 = Ce[kk + 2], ce3 = Ce[kk + 3];
#pragma unroll
      for (int ri = 0; ri < 8; ++ri) {
        const float Ar = A_reg[ri];
        const float d0 = (Ar - 2.0f * acc[ri][0]) + ce0;
        const float d1 = (Ar - 2.0f * acc[ri][1]) + ce1;
        const float d2 = (Ar - 2.0f * acc[ri][2]) + ce2;
        const float d3 = (Ar - 2.0f * acc[ri][3]) + ce3;
        if (d0 < best[ri]) { best[ri] = d0; bidx[ri] = kk; }
        if (d1 < best[ri]) { best[ri] = d1; bidx[ri] = kk + 1; }
        if (d2 < best[ri]) { best[ri] = d2; bidx[ri] = kk + 2; }
        if (d3 < best[ri]) { best[ri] = d3; bidx[ri] = kk + 3; }
        acc[ri][0] = 0.f; acc[ri][1] = 0.f; acc[ri][2] = 0.f; acc[ri][3] = 0.f;
      }
    }
  }

  // cross-thread argmin per row (tie -> lower absolute index)
#pragma unroll
  for (int ri = 0; ri < 8; ++ri) {
    redd[(ty * 8 + ri) * 32 + tx] = best[ri];
    redi[(ty * 8 + ri) * 32 + tx] = bidx[ri];
  }
  __syncthreads();
  if (t < 64) {
    float bd = redd[t * 32];
    int   bi = redi[t * 32];
    for (int j = 1; j < 32; ++j) {
      const float d  = redd[t * 32 + j];
      const int   i2 = redi[t * 32 + j];
      if (d < bd || (d == bd && i2 < bi)) { bd = d; bi = i2; }
    }
    const int n = rbase + t;
    cand_d[n * 4 + slice] = bd;
    cand_i[n * 4 + slice] = bi;
  }
}

// -------- merge the 4 code-slices (tie -> lower index) --------
__global__ void vq_merge_k(const float* __restrict__ cand_d, const int* __restrict__ cand_i,
                           int* __restrict__ idx_final, float* __restrict__ idxf_out) {
  const int n = blockIdx.x * 256 + threadIdx.x;   // 16384
  float bd = cand_d[n * 4];
  int   bi = cand_i[n * 4];
#pragma unroll
  for (int s = 1; s < 4; ++s) {
    const float d  = cand_d[n * 4 + s];
    const int   i2 = cand_i[n * 4 + s];
    if (d < bd || (d == bd && i2 < bi)) { bd = d; bi = i2; }
  }
  idx_final[n] = bi;
  idxf_out[n] = (float)bi;
}

// -------- gather quantized, write straight-through output, accumulate loss ----
// quantized_st = z + (q - z) in fp32 (matches np rounding; != q exactly).
__launch_bounds__(256)
__global__ void vq_gather_loss_k(const float* __restrict__ z, const float* __restrict__ emb,
                                 const int* __restrict__ idx_final,
                                 float* __restrict__ qout, float* __restrict__ loss_acc) {
  __shared__ float Qs[32 * 260];
  __shared__ int   kidx[32];
  __shared__ float warp_s[4];
  const int t = threadIdx.x;
  const int rbase = blockIdx.x * 32;
  if (t < 32) kidx[t] = idx_final[rbase + t];
  __syncthreads();
  {
    const int r = t >> 3, cp = t & 7;
    const float4* er = (const float4*)(emb + (size_t)kidx[r] * CDIM);
#pragma unroll
    for (int j = 0; j < 8; ++j) {
      const int c4 = cp + j * 8;
      const float4 v = er[c4];
      *(float4*)&Qs[r * 260 + c4 * 4] = v;
    }
  }
  __syncthreads();
  const int b = rbase >> 10, hw0 = rbase & 1023;
  const float* zb = z + (size_t)b * BSTRIDE + hw0;
  float* qb = qout + (size_t)b * BSTRIDE + hw0;
  float s = 0.f;
  const int hwl = t & 31, cg = t >> 5;
  for (int i = 0; i < 32; ++i) {
    const int c = cg * 32 + i;
    const float q  = Qs[hwl * 260 + c];
    const size_t off = (size_t)c * HWS + hwl;
    const float zv = zb[off];
    const float d  = q - zv;
    qb[off] = zv + d;          // straight-through value, np rounding
    s += d * d;
  }
  for (int off = 32; off; off >>= 1) s += __shfl_down(s, off, 64);
  if ((t & 63) == 0) warp_s[t >> 6] = s;
  __syncthreads();
  if (t == 0) atomicAdd(loss_acc, warp_s[0] + warp_s[1] + warp_s[2] + warp_s[3]);
}

__global__ void vq_finalize_k(const float* __restrict__ loss_acc, float* __restrict__ out_loss) {
  const float m = loss_acc[0] * (1.0f / 4194304.0f);
  out_loss[0] = m;          // codebook_loss
  out_loss[1] = 0.25f * m;  // commitment_loss (BETA * same mean)
}

extern "C" void kernel_launch(void* const* d_in, const int* in_sizes, int n_in,
                              void* d_out, int out_size, void* d_ws, size_t ws_size,
                              hipStream_t stream) {
  (void)in_sizes; (void)n_in; (void)out_size; (void)ws_size;
  const float* z   = (const float*)d_in[0];
  const float* emb = (const float*)d_in[1];
  float* out      = (float*)d_out;
  float* q_out    = out;                 // [16,256,32,32]
  float* loss_out = out + 4194304;       // 2 scalars
  float* idxf_out = out + 4194306;       // [16,32,32] as float

  float* ws       = (float*)d_ws;
  float* An       = ws + WS_AN;
  float* Ce       = ws + WS_CE;
  float* cand_d   = ws + WS_CD;
  int*   cand_i   = (int*)(ws + WS_CI);
  int*   idx_fin  = (int*)(ws + WS_IDX);
  float* loss_acc = ws + WS_LOSS;

  hipMemsetAsync(loss_acc, 0, sizeof(float), stream);
  rownorm_z_k<<<64, 256, 0, stream>>>(z, An);
  rownorm_e_k<<<32, 256, 0, stream>>>(emb, Ce);
  vq_argmin_k<<<1024, 256, 0, stream>>>(z, emb, An, Ce, cand_d, cand_i);
  vq_merge_k<<<64, 256, 0, stream>>>(cand_d, cand_i, idx_fin, idxf_out);
  vq_gather_loss_k<<<512, 256, 0, stream>>>(z, emb, idx_fin, q_out, loss_acc);
  vq_finalize_k<<<1, 1, 0, stream>>>(loss_acc, loss_out);
}

// Round 3
// 1086.336 us; speedup vs baseline: 2.4661x; 2.4661x over previous
//
#include <hip/hip_runtime.h>

// Problem constants
#define NROWS   16384      // 16*32*32 flattened (b,h,w) rows
#define KCODES  8192
#define CDIM    256
#define HWS     1024       // 32*32
#define BSTRIDE 262144     // 256*1024 floats per batch in z / out

// Workspace layout (float-unit offsets)
#define WS_AN   0                         // ||x||^2 per row       [16384]
#define WS_CE   16384                     // ||e||^2 per code      [8192]
#define WS_CD   24576                     // cand dist [n*4+slice] [65536]
#define WS_CI   90112                     // cand idx  (int)       [65536]
#define WS_IDX  155648                    // final idx (int)       [16384]
#define WS_LOSS 172032                    // loss accumulator      [1]

// -------- row norms, replicating numpy pairwise_sum order exactly --------
__global__ void rownorm_z_k(const float* __restrict__ z, float* __restrict__ An) {
#pragma clang fp contract(off)
  int n = blockIdx.x * 256 + threadIdx.x;                    // 16384 threads
  const float* base = z + ((size_t)(n >> 10)) * BSTRIDE + (n & 1023);
  float hs[2];
  for (int h = 0; h < 2; ++h) {
    float r[8];
#pragma unroll
    for (int j = 0; j < 8; ++j) { float v = base[(size_t)(h * 128 + j) * HWS]; r[j] = v * v; }
    for (int m = 1; m < 16; ++m) {
#pragma unroll
      for (int j = 0; j < 8; ++j) { float v = base[(size_t)(h * 128 + m * 8 + j) * HWS]; r[j] += v * v; }
    }
    hs[h] = ((r[0] + r[1]) + (r[2] + r[3])) + ((r[4] + r[5]) + (r[6] + r[7]));
  }
  An[n] = hs[0] + hs[1];
}

__global__ void rownorm_e_k(const float* __restrict__ emb, float* __restrict__ Ce) {
#pragma clang fp contract(off)
  int n = blockIdx.x * 256 + threadIdx.x;                    // 8192 threads
  const float* base = emb + (size_t)n * CDIM;
  float hs[2];
  for (int h = 0; h < 2; ++h) {
    float r[8];
#pragma unroll
    for (int j = 0; j < 8; ++j) { float v = base[h * 128 + j]; r[j] = v * v; }
    for (int m = 1; m < 16; ++m) {
#pragma unroll
      for (int j = 0; j < 8; ++j) { float v = base[h * 128 + m * 8 + j]; r[j] += v * v; }
    }
    hs[h] = ((r[0] + r[1]) + (r[2] + r[3])) + ((r[4] + r[5]) + (r[6] + r[7]));
  }
  Ce[n] = hs[0] + hs[1];
}

// -------- fused distance + argmin --------
// 2048 blocks = 512 row-tiles (32 rows) x 4 code-slices (2048 codes each).
// 256 threads = 32 tx (codes, 4 each) x 8 ty (rows, 4 each). Micro-tile 4x4.
//
// Register budget is the design driver (rounds 1-2): the allocator targets
// 8 waves/EU (64 VGPR) and spills anything bigger (4-7 GB scratch traffic in
// WRITE_SIZE). 4x4 tile keeps peak live ~56-60 regs -> zero spills at 64.
// Global loads are issued just before barrier #1 so latency hides under the
// barrier wait, without holding prefetch regs across the compute phase.
// As stride 20: (r*20+g*4)*4B is 16B-aligned -> ds_read_b128 (stride 21 in
// round 2 broke alignment -> 4x ds_read_b32). float2 As staging makes the
// store pattern 4-way (only 2 stores/chunk; negligible).
__global__ void __launch_bounds__(256)
vq_argmin_k(const float* __restrict__ z, const float* __restrict__ emb,
            const float* __restrict__ An, const float* __restrict__ Ce,
            float* __restrict__ cand_d, int* __restrict__ cand_i) {
  __shared__ float As[32 * 20];    // [row][c_local], stride 20 (16B-aligned reads)
  __shared__ float Bs[16 * 132];   // [c_local][code], 2-way max on stores (free)
  __shared__ float redd[32 * 32];
  __shared__ int   redi[32 * 32];

  const int t  = threadIdx.x;
  const int tx = t & 31;
  const int ty = t >> 5;
  const int tile  = blockIdx.x >> 2;
  const int slice = blockIdx.x & 3;
  const int rbase = tile * 32;
  const int k0    = slice * 2048;

  const float* zb = z + ((size_t)(rbase >> 10)) * BSTRIDE + (rbase & 1023);

  float A_reg[4];
#pragma unroll
  for (int ri = 0; ri < 4; ++ri) A_reg[ri] = An[rbase + ty * 4 + ri];

  float best[4];
  int   bidx[4];
#pragma unroll
  for (int ri = 0; ri < 4; ++ri) { best[ri] = 3.4028235e38f; bidx[ri] = 0; }

  float acc[4][4];
#pragma unroll
  for (int ri = 0; ri < 4; ++ri)
#pragma unroll
    for (int ki = 0; ki < 4; ++ki) acc[ri][ki] = 0.f;

  // staging thread mappings
  const int a_c  = t >> 4;          // c_local 0..15
  const int a_hw = (t & 15) * 2;    // 2 consecutive hw (rows) via float2
  const int b_ks = t >> 2;          // code 0..63 (and +64)
  const int b_cp = (t & 3) * 4;     // c_local offset 0/4/8/12 (64B-contig rows)

  const int iters = 16 * (2048 / 128);   // 16 c-chunks * 16 code-chunks = 256
  for (int it = 0; it < iters; ++it) {
    const int cc = it & 15;
    const int kb = k0 + (it >> 4) * 128;

    // issue global loads BEFORE the barrier: latency overlaps barrier wait,
    // registers die at the LDS stores (not held across compute)
    const float2 pa = *(const float2*)(zb + (size_t)(cc * 16 + a_c) * HWS + a_hw);
    const float4 pb0 = *(const float4*)(emb + (size_t)(kb + b_ks) * CDIM + cc * 16 + b_cp);
    const float4 pb1 = *(const float4*)(emb + (size_t)(kb + b_ks + 64) * CDIM + cc * 16 + b_cp);

    __syncthreads();                      // prior compute done with As/Bs
    As[(a_hw + 0) * 20 + a_c] = pa.x;     // transpose hw-major load -> [row][c]
    As[(a_hw + 1) * 20 + a_c] = pa.y;
    Bs[(b_cp + 0) * 132 + b_ks] = pb0.x;
    Bs[(b_cp + 1) * 132 + b_ks] = pb0.y;
    Bs[(b_cp + 2) * 132 + b_ks] = pb0.z;
    Bs[(b_cp + 3) * 132 + b_ks] = pb0.w;
    Bs[(b_cp + 0) * 132 + b_ks + 64] = pb1.x;
    Bs[(b_cp + 1) * 132 + b_ks + 64] = pb1.y;
    Bs[(b_cp + 2) * 132 + b_ks + 64] = pb1.z;
    Bs[(b_cp + 3) * 132 + b_ks + 64] = pb1.w;
    __syncthreads();                      // staged data visible

    // 4x4 micro-tile over 16 c: 256 fp32 FMAs / thread
    // (accumulation order bit-identical to the round-1 passing kernel)
#pragma unroll
    for (int g = 0; g < 4; ++g) {
      const float4 b0 = *(const float4*)&Bs[(g * 4 + 0) * 132 + tx * 4];
      const float4 b1 = *(const float4*)&Bs[(g * 4 + 1) * 132 + tx * 4];
      const float4 b2 = *(const float4*)&Bs[(g * 4 + 2) * 132 + tx * 4];
      const float4 b3 = *(const float4*)&Bs[(g * 4 + 3) * 132 + tx * 4];
#pragma unroll
      for (int ri = 0; ri < 4; ++ri) {
        const float4 a = *(const float4*)&As[(ty * 4 + ri) * 20 + g * 4];
        acc[ri][0] = fmaf(a.x, b0.x, fmaf(a.y, b1.x, fmaf(a.z, b2.x, fmaf(a.w, b3.x, acc[ri][0]))));
        acc[ri][1] = fmaf(a.x, b0.y, fmaf(a.y, b1.y, fmaf(a.z, b2.y, fmaf(a.w, b3.y, acc[ri][1]))));
        acc[ri][2] = fmaf(a.x, b0.z, fmaf(a.y, b1.z, fmaf(a.z, b2.z, fmaf(a.w, b3.z, acc[ri][2]))));
        acc[ri][3] = fmaf(a.x, b0.w, fmaf(a.y, b1.w, fmaf(a.z, b2.w, fmaf(a.w, b3.w, acc[ri][3]))));
      }
    }

    if (cc == 15) {
      // fold: dist = (A - 2*dot) + C with np's elementwise fp32 rounding.
      // k ascending + strict < keeps lowest-index min, matching np.argmin ties.
      const int kk = kb + tx * 4;
      const float4 ce = *(const float4*)&Ce[kk];
#pragma unroll
      for (int ri = 0; ri < 4; ++ri) {
        const float Ar = A_reg[ri];
        const float d0 = (Ar - 2.0f * acc[ri][0]) + ce.x;
        const float d1 = (Ar - 2.0f * acc[ri][1]) + ce.y;
        const float d2 = (Ar - 2.0f * acc[ri][2]) + ce.z;
        const float d3 = (Ar - 2.0f * acc[ri][3]) + ce.w;
        if (d0 < best[ri]) { best[ri] = d0; bidx[ri] = kk; }
        if (d1 < best[ri]) { best[ri] = d1; bidx[ri] = kk + 1; }
        if (d2 < best[ri]) { best[ri] = d2; bidx[ri] = kk + 2; }
        if (d3 < best[ri]) { best[ri] = d3; bidx[ri] = kk + 3; }
        acc[ri][0] = 0.f; acc[ri][1] = 0.f; acc[ri][2] = 0.f; acc[ri][3] = 0.f;
      }
    }
  }

  // cross-thread argmin per row (tie -> lower absolute index)
#pragma unroll
  for (int ri = 0; ri < 4; ++ri) {
    redd[(ty * 4 + ri) * 32 + tx] = best[ri];
    redi[(ty * 4 + ri) * 32 + tx] = bidx[ri];
  }
  __syncthreads();
  if (t < 32) {
    float bd = redd[t * 32];
    int   bi = redi[t * 32];
    for (int j = 1; j < 32; ++j) {
      const float d  = redd[t * 32 + j];
      const int   i2 = redi[t * 32 + j];
      if (d < bd || (d == bd && i2 < bi)) { bd = d; bi = i2; }
    }
    const int n = rbase + t;
    cand_d[n * 4 + slice] = bd;
    cand_i[n * 4 + slice] = bi;
  }
}

// -------- merge the 4 code-slices (tie -> lower index) --------
__global__ void vq_merge_k(const float* __restrict__ cand_d, const int* __restrict__ cand_i,
                           int* __restrict__ idx_final, float* __restrict__ idxf_out) {
  const int n = blockIdx.x * 256 + threadIdx.x;   // 16384
  float bd = cand_d[n * 4];
  int   bi = cand_i[n * 4];
#pragma unroll
  for (int s = 1; s < 4; ++s) {
    const float d  = cand_d[n * 4 + s];
    const int   i2 = cand_i[n * 4 + s];
    if (d < bd || (d == bd && i2 < bi)) { bd = d; bi = i2; }
  }
  idx_final[n] = bi;
  idxf_out[n] = (float)bi;
}

// -------- gather quantized, write straight-through output, accumulate loss ----
// quantized_st = z + (q - z) in fp32 (matches np rounding; != q exactly).
__launch_bounds__(256)
__global__ void vq_gather_loss_k(const float* __restrict__ z, const float* __restrict__ emb,
                                 const int* __restrict__ idx_final,
                                 float* __restrict__ qout, float* __restrict__ loss_acc) {
  __shared__ float Qs[32 * 260];
  __shared__ int   kidx[32];
  __shared__ float warp_s[4];
  const int t = threadIdx.x;
  const int rbase = blockIdx.x * 32;
  if (t < 32) kidx[t] = idx_final[rbase + t];
  __syncthreads();
  {
    const int r = t >> 3, cp = t & 7;
    const float4* er = (const float4*)(emb + (size_t)kidx[r] * CDIM);
#pragma unroll
    for (int j = 0; j < 8; ++j) {
      const int c4 = cp + j * 8;
      const float4 v = er[c4];
      *(float4*)&Qs[r * 260 + c4 * 4] = v;
    }
  }
  __syncthreads();
  const int b = rbase >> 10, hw0 = rbase & 1023;
  const float* zb = z + (size_t)b * BSTRIDE + hw0;
  float* qb = qout + (size_t)b * BSTRIDE + hw0;
  float s = 0.f;
  const int hwl = t & 31, cg = t >> 5;
  for (int i = 0; i < 32; ++i) {
    const int c = cg * 32 + i;
    const float q  = Qs[hwl * 260 + c];
    const size_t off = (size_t)c * HWS + hwl;
    const float zv = zb[off];
    const float d  = q - zv;
    qb[off] = zv + d;          // straight-through value, np rounding
    s += d * d;
  }
  for (int off = 32; off; off >>= 1) s += __shfl_down(s, off, 64);
  if ((t & 63) == 0) warp_s[t >> 6] = s;
  __syncthreads();
  if (t == 0) atomicAdd(loss_acc, warp_s[0] + warp_s[1] + warp_s[2] + warp_s[3]);
}

__global__ void vq_finalize_k(const float* __restrict__ loss_acc, float* __restrict__ out_loss) {
  const float m = loss_acc[0] * (1.0f / 4194304.0f);
  out_loss[0] = m;          // codebook_loss
  out_loss[1] = 0.25f * m;  // commitment_loss (BETA * same mean)
}

extern "C" void kernel_launch(void* const* d_in, const int* in_sizes, int n_in,
                              void* d_out, int out_size, void* d_ws, size_t ws_size,
                              hipStream_t stream) {
  (void)in_sizes; (void)n_in; (void)out_size; (void)ws_size;
  const float* z   = (const float*)d_in[0];
  const float* emb = (const float*)d_in[1];
  float* out      = (float*)d_out;
  float* q_out    = out;                 // [16,256,32,32]
  float* loss_out = out + 4194304;       // 2 scalars
  float* idxf_out = out + 4194306;       // [16,32,32] as float

  float* ws       = (float*)d_ws;
  float* An       = ws + WS_AN;
  float* Ce       = ws + WS_CE;
  float* cand_d   = ws + WS_CD;
  int*   cand_i   = (int*)(ws + WS_CI);
  int*   idx_fin  = (int*)(ws + WS_IDX);
  float* loss_acc = ws + WS_LOSS;

  hipMemsetAsync(loss_acc, 0, sizeof(float), stream);
  rownorm_z_k<<<64, 256, 0, stream>>>(z, An);
  rownorm_e_k<<<32, 256, 0, stream>>>(emb, Ce);
  vq_argmin_k<<<2048, 256, 0, stream>>>(z, emb, An, Ce, cand_d, cand_i);
  vq_merge_k<<<64, 256, 0, stream>>>(cand_d, cand_i, idx_fin, idxf_out);
  vq_gather_loss_k<<<512, 256, 0, stream>>>(z, emb, idx_fin, q_out, loss_acc);
  vq_finalize_k<<<1, 1, 0, stream>>>(loss_acc, loss_out);
}

// Round 4
// 1069.196 us; speedup vs baseline: 2.5057x; 1.0160x over previous
//
#include <hip/hip_runtime.h>

// Problem constants
#define NROWS   16384      // 16*32*32 flattened (b,h,w) rows
#define KCODES  8192
#define CDIM    256
#define HWS     1024       // 32*32
#define BSTRIDE 262144     // 256*1024 floats per batch in z / out

// Workspace layout (float-unit offsets)
#define WS_AN   0                         // ||x||^2 per row       [16384]
#define WS_CE   16384                     // ||e||^2 per code      [8192]
#define WS_CD   24576                     // cand dist [n*4+slice] [65536]
#define WS_CI   90112                     // cand idx  (int)       [65536]
#define WS_IDX  155648                    // final idx (int)       [16384]
#define WS_LOSS 172032                    // loss accumulator      [1]

// -------- row norms, replicating numpy pairwise_sum order exactly --------
__global__ void rownorm_z_k(const float* __restrict__ z, float* __restrict__ An) {
#pragma clang fp contract(off)
  int n = blockIdx.x * 256 + threadIdx.x;                    // 16384 threads
  const float* base = z + ((size_t)(n >> 10)) * BSTRIDE + (n & 1023);
  float hs[2];
  for (int h = 0; h < 2; ++h) {
    float r[8];
#pragma unroll
    for (int j = 0; j < 8; ++j) { float v = base[(size_t)(h * 128 + j) * HWS]; r[j] = v * v; }
    for (int m = 1; m < 16; ++m) {
#pragma unroll
      for (int j = 0; j < 8; ++j) { float v = base[(size_t)(h * 128 + m * 8 + j) * HWS]; r[j] += v * v; }
    }
    hs[h] = ((r[0] + r[1]) + (r[2] + r[3])) + ((r[4] + r[5]) + (r[6] + r[7]));
  }
  An[n] = hs[0] + hs[1];
}

__global__ void rownorm_e_k(const float* __restrict__ emb, float* __restrict__ Ce) {
#pragma clang fp contract(off)
  int n = blockIdx.x * 256 + threadIdx.x;                    // 8192 threads
  const float* base = emb + (size_t)n * CDIM;
  float hs[2];
  for (int h = 0; h < 2; ++h) {
    float r[8];
#pragma unroll
    for (int j = 0; j < 8; ++j) { float v = base[h * 128 + j]; r[j] = v * v; }
    for (int m = 1; m < 16; ++m) {
#pragma unroll
      for (int j = 0; j < 8; ++j) { float v = base[h * 128 + m * 8 + j]; r[j] += v * v; }
    }
    hs[h] = ((r[0] + r[1]) + (r[2] + r[3])) + ((r[4] + r[5]) + (r[6] + r[7]));
  }
  Ce[n] = hs[0] + hs[1];
}

// -------- fused distance + argmin --------
// 2048 blocks = 512 row-tiles (32 rows) x 4 code-slices (2048 codes each).
// 256 threads = 32 tx (codes, 4 each) x 8 ty (rows, 4 each). Micro-tile 4x4.
//
// Register budget is the design driver (rounds 1-3): allocator targets 8
// waves/EU (64 VGPR); 4x4 tile + 10 prefetch regs ~= 56-60 live -> no spill
// (round 3 measured 44 without prefetch; WRITE_SIZE is the spill tripwire).
// LONG prefetch (round 3 lesson): loads for it+1 are issued before the
// 512-cycle compute phase, so the ~200-400 cyc L2 latency is hidden under
// compute instead of stalling at vmcnt(0) right after barrier #1 (that stall
// was the round-3 1031us vs 437us-floor gap).
// As stride 20: (r*20+g*4)*4B is 16B-aligned -> ds_read_b128.
__global__ void __launch_bounds__(256)
vq_argmin_k(const float* __restrict__ z, const float* __restrict__ emb,
            const float* __restrict__ An, const float* __restrict__ Ce,
            float* __restrict__ cand_d, int* __restrict__ cand_i) {
  __shared__ float As[32 * 20];    // [row][c_local], stride 20 (16B-aligned reads)
  __shared__ float Bs[16 * 132];   // [c_local][code], 2-way max on stores (free)
  __shared__ float redd[32 * 32];
  __shared__ int   redi[32 * 32];

  const int t  = threadIdx.x;
  const int tx = t & 31;
  const int ty = t >> 5;
  const int tile  = blockIdx.x >> 2;
  const int slice = blockIdx.x & 3;
  const int rbase = tile * 32;
  const int k0    = slice * 2048;

  const float* zb = z + ((size_t)(rbase >> 10)) * BSTRIDE + (rbase & 1023);

  float A_reg[4];
#pragma unroll
  for (int ri = 0; ri < 4; ++ri) A_reg[ri] = An[rbase + ty * 4 + ri];

  float best[4];
  int   bidx[4];
#pragma unroll
  for (int ri = 0; ri < 4; ++ri) { best[ri] = 3.4028235e38f; bidx[ri] = 0; }

  float acc[4][4];
#pragma unroll
  for (int ri = 0; ri < 4; ++ri)
#pragma unroll
    for (int ki = 0; ki < 4; ++ki) acc[ri][ki] = 0.f;

  // staging thread mappings
  const int a_c  = t >> 4;          // c_local 0..15
  const int a_hw = (t & 15) * 2;    // 2 consecutive hw (rows) via float2
  const int b_ks = t >> 2;          // code 0..63 (and +64)
  const int b_cp = (t & 3) * 4;     // c_local offset 0/4/8/12 (64B-contig rows)

  // prefetch chunk 0
  float2 pa  = *(const float2*)(zb + (size_t)(a_c) * HWS + a_hw);
  float4 pb0 = *(const float4*)(emb + (size_t)(k0 + b_ks) * CDIM + b_cp);
  float4 pb1 = *(const float4*)(emb + (size_t)(k0 + b_ks + 64) * CDIM + b_cp);

  const int iters = 16 * (2048 / 128);   // 16 c-chunks * 16 code-chunks = 256
  for (int it = 0; it < iters; ++it) {
    const int cc = it & 15;
    const int kb = k0 + (it >> 4) * 128;

    __syncthreads();                      // prior compute done with As/Bs
    As[(a_hw + 0) * 20 + a_c] = pa.x;     // transpose hw-major load -> [row][c]
    As[(a_hw + 1) * 20 + a_c] = pa.y;
    Bs[(b_cp + 0) * 132 + b_ks] = pb0.x;
    Bs[(b_cp + 1) * 132 + b_ks] = pb0.y;
    Bs[(b_cp + 2) * 132 + b_ks] = pb0.z;
    Bs[(b_cp + 3) * 132 + b_ks] = pb0.w;
    Bs[(b_cp + 0) * 132 + b_ks + 64] = pb1.x;
    Bs[(b_cp + 1) * 132 + b_ks + 64] = pb1.y;
    Bs[(b_cp + 2) * 132 + b_ks + 64] = pb1.z;
    Bs[(b_cp + 3) * 132 + b_ks + 64] = pb1.w;
    __syncthreads();                      // staged data visible

    // long prefetch: issue loads for it+1 BEFORE compute; ~300 cyc latency
    // hides under the 512-cycle FMA phase (regs stay live across compute,
    // total ~58 VGPR -- fits the 64-reg/8-wave budget, no spill)
    if (it + 1 < iters) {
      const int ncc = (it + 1) & 15;
      const int nkb = k0 + ((it + 1) >> 4) * 128;
      pa  = *(const float2*)(zb + (size_t)(ncc * 16 + a_c) * HWS + a_hw);
      pb0 = *(const float4*)(emb + (size_t)(nkb + b_ks) * CDIM + ncc * 16 + b_cp);
      pb1 = *(const float4*)(emb + (size_t)(nkb + b_ks + 64) * CDIM + ncc * 16 + b_cp);
    }

    // 4x4 micro-tile over 16 c: 256 fp32 FMAs / thread
    // (accumulation order bit-identical to the round-1 passing kernel)
#pragma unroll
    for (int g = 0; g < 4; ++g) {
      const float4 b0 = *(const float4*)&Bs[(g * 4 + 0) * 132 + tx * 4];
      const float4 b1 = *(const float4*)&Bs[(g * 4 + 1) * 132 + tx * 4];
      const float4 b2 = *(const float4*)&Bs[(g * 4 + 2) * 132 + tx * 4];
      const float4 b3 = *(const float4*)&Bs[(g * 4 + 3) * 132 + tx * 4];
#pragma unroll
      for (int ri = 0; ri < 4; ++ri) {
        const float4 a = *(const float4*)&As[(ty * 4 + ri) * 20 + g * 4];
        acc[ri][0] = fmaf(a.x, b0.x, fmaf(a.y, b1.x, fmaf(a.z, b2.x, fmaf(a.w, b3.x, acc[ri][0]))));
        acc[ri][1] = fmaf(a.x, b0.y, fmaf(a.y, b1.y, fmaf(a.z, b2.y, fmaf(a.w, b3.y, acc[ri][1]))));
        acc[ri][2] = fmaf(a.x, b0.z, fmaf(a.y, b1.z, fmaf(a.z, b2.z, fmaf(a.w, b3.z, acc[ri][2]))));
        acc[ri][3] = fmaf(a.x, b0.w, fmaf(a.y, b1.w, fmaf(a.z, b2.w, fmaf(a.w, b3.w, acc[ri][3]))));
      }
    }

    if (cc == 15) {
      // fold: dist = (A - 2*dot) + C with np's elementwise fp32 rounding.
      // k ascending + strict < keeps lowest-index min, matching np.argmin ties.
      const int kk = kb + tx * 4;
      const float4 ce = *(const float4*)&Ce[kk];
#pragma unroll
      for (int ri = 0; ri < 4; ++ri) {
        const float Ar = A_reg[ri];
        const float d0 = (Ar - 2.0f * acc[ri][0]) + ce.x;
        const float d1 = (Ar - 2.0f * acc[ri][1]) + ce.y;
        const float d2 = (Ar - 2.0f * acc[ri][2]) + ce.z;
        const float d3 = (Ar - 2.0f * acc[ri][3]) + ce.w;
        if (d0 < best[ri]) { best[ri] = d0; bidx[ri] = kk; }
        if (d1 < best[ri]) { best[ri] = d1; bidx[ri] = kk + 1; }
        if (d2 < best[ri]) { best[ri] = d2; bidx[ri] = kk + 2; }
        if (d3 < best[ri]) { best[ri] = d3; bidx[ri] = kk + 3; }
        acc[ri][0] = 0.f; acc[ri][1] = 0.f; acc[ri][2] = 0.f; acc[ri][3] = 0.f;
      }
    }
  }

  // cross-thread argmin per row (tie -> lower absolute index)
#pragma unroll
  for (int ri = 0; ri < 4; ++ri) {
    redd[(ty * 4 + ri) * 32 + tx] = best[ri];
    redi[(ty * 4 + ri) * 32 + tx] = bidx[ri];
  }
  __syncthreads();
  if (t < 32) {
    float bd = redd[t * 32];
    int   bi = redi[t * 32];
    for (int j = 1; j < 32; ++j) {
      const float d  = redd[t * 32 + j];
      const int   i2 = redi[t * 32 + j];
      if (d < bd || (d == bd && i2 < bi)) { bd = d; bi = i2; }
    }
    const int n = rbase + t;
    cand_d[n * 4 + slice] = bd;
    cand_i[n * 4 + slice] = bi;
  }
}

// -------- merge the 4 code-slices (tie -> lower index) --------
__global__ void vq_merge_k(const float* __restrict__ cand_d, const int* __restrict__ cand_i,
                           int* __restrict__ idx_final, float* __restrict__ idxf_out) {
  const int n = blockIdx.x * 256 + threadIdx.x;   // 16384
  float bd = cand_d[n * 4];
  int   bi = cand_i[n * 4];
#pragma unroll
  for (int s = 1; s < 4; ++s) {
    const float d  = cand_d[n * 4 + s];
    const int   i2 = cand_i[n * 4 + s];
    if (d < bd || (d == bd && i2 < bi)) { bd = d; bi = i2; }
  }
  idx_final[n] = bi;
  idxf_out[n] = (float)bi;
}

// -------- gather quantized, write straight-through output, accumulate loss ----
// quantized_st = z + (q - z) in fp32 (matches np rounding; != q exactly).
__launch_bounds__(256)
__global__ void vq_gather_loss_k(const float* __restrict__ z, const float* __restrict__ emb,
                                 const int* __restrict__ idx_final,
                                 float* __restrict__ qout, float* __restrict__ loss_acc) {
  __shared__ float Qs[32 * 260];
  __shared__ int   kidx[32];
  __shared__ float warp_s[4];
  const int t = threadIdx.x;
  const int rbase = blockIdx.x * 32;
  if (t < 32) kidx[t] = idx_final[rbase + t];
  __syncthreads();
  {
    const int r = t >> 3, cp = t & 7;
    const float4* er = (const float4*)(emb + (size_t)kidx[r] * CDIM);
#pragma unroll
    for (int j = 0; j < 8; ++j) {
      const int c4 = cp + j * 8;
      const float4 v = er[c4];
      *(float4*)&Qs[r * 260 + c4 * 4] = v;
    }
  }
  __syncthreads();
  const int b = rbase >> 10, hw0 = rbase & 1023;
  const float* zb = z + (size_t)b * BSTRIDE + hw0;
  float* qb = qout + (size_t)b * BSTRIDE + hw0;
  float s = 0.f;
  const int hwl = t & 31, cg = t >> 5;
  for (int i = 0; i < 32; ++i) {
    const int c = cg * 32 + i;
    const float q  = Qs[hwl * 260 + c];
    const size_t off = (size_t)c * HWS + hwl;
    const float zv = zb[off];
    const float d  = q - zv;
    qb[off] = zv + d;          // straight-through value, np rounding
    s += d * d;
  }
  for (int off = 32; off; off >>= 1) s += __shfl_down(s, off, 64);
  if ((t & 63) == 0) warp_s[t >> 6] = s;
  __syncthreads();
  if (t == 0) atomicAdd(loss_acc, warp_s[0] + warp_s[1] + warp_s[2] + warp_s[3]);
}

__global__ void vq_finalize_k(const float* __restrict__ loss_acc, float* __restrict__ out_loss) {
  const float m = loss_acc[0] * (1.0f / 4194304.0f);
  out_loss[0] = m;          // codebook_loss
  out_loss[1] = 0.25f * m;  // commitment_loss (BETA * same mean)
}

extern "C" void kernel_launch(void* const* d_in, const int* in_sizes, int n_in,
                              void* d_out, int out_size, void* d_ws, size_t ws_size,
                              hipStream_t stream) {
  (void)in_sizes; (void)n_in; (void)out_size; (void)ws_size;
  const float* z   = (const float*)d_in[0];
  const float* emb = (const float*)d_in[1];
  float* out      = (float*)d_out;
  float* q_out    = out;                 // [16,256,32,32]
  float* loss_out = out + 4194304;       // 2 scalars
  float* idxf_out = out + 4194306;       // [16,32,32] as float

  float* ws       = (float*)d_ws;
  float* An       = ws + WS_AN;
  float* Ce       = ws + WS_CE;
  float* cand_d   = ws + WS_CD;
  int*   cand_i   = (int*)(ws + WS_CI);
  int*   idx_fin  = (int*)(ws + WS_IDX);
  float* loss_acc = ws + WS_LOSS;

  hipMemsetAsync(loss_acc, 0, sizeof(float), stream);
  rownorm_z_k<<<64, 256, 0, stream>>>(z, An);
  rownorm_e_k<<<32, 256, 0, stream>>>(emb, Ce);
  vq_argmin_k<<<2048, 256, 0, stream>>>(z, emb, An, Ce, cand_d, cand_i);
  vq_merge_k<<<64, 256, 0, stream>>>(cand_d, cand_i, idx_fin, idxf_out);
  vq_gather_loss_k<<<512, 256, 0, stream>>>(z, emb, idx_fin, q_out, loss_acc);
  vq_finalize_k<<<1, 1, 0, stream>>>(loss_acc, loss_out);
}